// Round 14
// baseline (52.893 us; speedup 1.0000x reference)
//
#include <hip/hip_runtime.h>
#include <hip/hip_bf16.h>

#define BB 4096   // batch
#define DD 64     // event dim
#define HH 512    // hidden

typedef short short8 __attribute__((ext_vector_type(8)));   // 8 bf16
typedef float f32x4  __attribute__((ext_vector_type(4)));
typedef __hip_bfloat16 bf16;

// branchless fast tanh: 1 - 2/(1+e^{2x}); exact limits at +-inf
__device__ __forceinline__ float tanh_fast(float x) {
    float e = __expf(2.0f * x);
    return 1.0f - __fdividef(2.0f, 1.0f + e);
}

// swizzled LDS bf16 store: 8-elem chunk XOR'd with row&7 (write side)
__device__ __forceinline__ void st_swz(bf16* base, int row, int col, int rs, float v) {
    base[row * rs + ((((col >> 3) ^ (row & 7))) << 3) + (col & 7)] = __float2bfloat16(v);
}

// single 1KB fragment load (proven R10/R12)
#define GLD1(dst, addr)                                                      \
  asm volatile("global_load_dwordx4 %0, %1, off" : "=&v"(dst) : "v"(addr))

// 2KB entry = 2 x 1KB
#define GLD2(e0, e1, addr)                                                   \
  asm volatile("global_load_dwordx4 %0, %2, off\n\t"                         \
               "global_load_dwordx4 %1, %2, off offset:1024"                 \
               : "=&v"(e0), "=&v"(e1) : "v"(addr))

// 4KB entry = 4 x 1KB
#define GLD4(e0, e1, e2, e3, addr)                                           \
  asm volatile("global_load_dwordx4 %0, %4, off\n\t"                         \
               "global_load_dwordx4 %1, %4, off offset:1024\n\t"             \
               "global_load_dwordx4 %2, %4, off offset:2048\n\t"             \
               "global_load_dwordx4 %3, %4, off offset:3072"                 \
               : "=&v"(e0), "=&v"(e1), "=&v"(e2), "=&v"(e3) : "v"(addr))

// counted wait + compiler motion fence (rule 18)
#define WAITV(n)                                                             \
  do { asm volatile("s_waitcnt vmcnt(" #n ")" ::: "memory");                 \
       __builtin_amdgcn_sched_barrier(0); } while (0)

// LDS-only barrier: raw s_barrier with lgkmcnt drain but NO vmcnt drain
#define LGKMBAR()                                                            \
  do { asm volatile("s_waitcnt lgkmcnt(0)" ::: "memory");                    \
       __builtin_amdgcn_s_barrier();                                         \
       __builtin_amdgcn_sched_barrier(0); } while (0)

// ===========================================================================
// Packed weights (16-col x 32-k tiles, tile = 512 elems = 1KB; lane l:
// kq=l>>4, r=l&15 owns B[col=base+r][k=kbase+kq*8+j], j=0..7 = 16B).
//   W1p: T = w*4 + s*2 + f   (w 0..15, s 0..1, f 0..1)  col=(w*2+f)*16+r
//   W2p: T = cw*16 + s       (cw 0..31, s 0..15)        col=cw*16+r
//   Pp : T = cw*16 + s       outcol k=cw*16+r, reduce j=s*32+kq*8+jj
//   W3p: T = q*4 + f         (q 0..15, f 0..3)          col=f*16+r, k=q*32+..
// ===========================================================================
__global__ __launch_bounds__(256) void prep_kernel(
    const float* __restrict__ t, const float* __restrict__ W1,
    const float* __restrict__ b1, const float* __restrict__ W2,
    const float* __restrict__ W3, const float* __restrict__ b3,
    bf16* __restrict__ W1p, bf16* __restrict__ W2p, bf16* __restrict__ W3p,
    bf16* __restrict__ Pp, float* __restrict__ b1eff, float* __restrict__ out)
{
    const int tid  = threadIdx.x;
    const int bx   = blockIdx.x;
    const int lane = tid & 63;
    const int r    = lane & 15;
    const int kq   = lane >> 4;

    if (bx < 160) {
        int T = bx * 4 + (tid >> 6);     // 0..639
        const float* src;
        bf16* dst;
        int stride;
        if (T < 64) {            // W1p
            int w = T >> 2, s = (T >> 1) & 1, f = T & 1;
            src = W1 + (size_t)(s * 32 + kq * 8) * HH + (w * 2 + f) * 16 + r;
            stride = HH;
            dst = W1p + (size_t)T * 512 + lane * 8;
        } else if (T < 576) {    // W2p
            int tt = T - 64;
            int cw = tt >> 4, s = tt & 15;
            src = W2 + (size_t)(s * 32 + kq * 8) * HH + cw * 16 + r;
            stride = HH;
            dst = W2p + (size_t)tt * 512 + lane * 8;
        } else {                 // W3p
            int tt = T - 576;
            int q = tt >> 2, f = tt & 3;
            src = W3 + (size_t)(q * 32 + kq * 8) * DD + f * 16 + r;
            stride = DD;
            dst = W3p + (size_t)tt * 512 + lane * 8;
        }
        short8 v;
#pragma unroll
        for (int j = 0; j < 8; ++j)
            v[j] = (short)__bfloat16_as_ushort(__float2bfloat16(src[(size_t)j * stride]));
        *(short8*)dst = v;
    } else if (bx < 288) {
        // Pp tile pt: out-col k = cw*16+r, reduce j = s*32+kq*8+jj
        int pt = (bx - 160) * 4 + (tid >> 6);    // 0..511
        int cw = pt >> 4, s = pt & 15;
        int k  = cw * 16 + r;
        int j0 = s * 32 + kq * 8;
        float acc[8] = {};
        const float* w3row = W3 + (size_t)k * DD;
        for (int d = 0; d < DD; ++d) {
            float w3 = w3row[d];
            const float4* w1p4 = (const float4*)(W1 + (size_t)d * HH + j0);
            float4 x = w1p4[0], y = w1p4[1];
            acc[0] += x.x * w3; acc[1] += x.y * w3;
            acc[2] += x.z * w3; acc[3] += x.w * w3;
            acc[4] += y.x * w3; acc[5] += y.y * w3;
            acc[6] += y.z * w3; acc[7] += y.w * w3;
        }
        short8 v;
#pragma unroll
        for (int j = 0; j < 8; ++j)
            v[j] = (short)__bfloat16_as_ushort(
                __float2bfloat16(acc[j] * W2[(size_t)(j0 + j) * HH + k]));
        *(short8*)(Pp + (size_t)pt * 512 + lane * 8) = v;
    } else if (bx == 288) {
        float tv = t[0];
        b1eff[tid]       = b1[tid]       + tv * W1[(size_t)64 * HH + tid];
        b1eff[tid + 256] = b1[tid + 256] + tv * W1[(size_t)64 * HH + tid + 256];
    } else {
        // init output: v region = b3 broadcast, trace region = 0
        int idx = (bx - 289) * 1024 + tid * 4;   // 260 blocks, exact cover
        if (idx < BB * DD) {
            int col = idx & 63;
            *(float4*)(out + idx) =
                make_float4(b3[col], b3[col + 1], b3[col + 2], b3[col + 3]);
        } else {
            *(float4*)(out + idx) = make_float4(0.f, 0.f, 0.f, 0.f);
        }
    }
}

// ---------------------------------------------------------------------------
// fused_rows: DIAGNOSTIC build -- merged L2||E loop executed REPS=3 times;
// reps 0-1 accumulate into the same registers (kept live via asm sink, then
// re-zeroed), rep 2 is the real pass. Outputs bit-identical to R13.
// dur delta / 2 = marginal cost of one merged-loop pass.
// ---------------------------------------------------------------------------
__global__ __launch_bounds__(1024, 2) void fused_rows(
    const float* __restrict__ z, const bf16* __restrict__ W1p,
    const bf16* __restrict__ W2p, const bf16* __restrict__ W3p,
    const bf16* __restrict__ Pp, const float* __restrict__ b1eff,
    const float* __restrict__ b2,
    float* __restrict__ outV, float* __restrict__ outTr)
{
    __shared__ alignas(16) char smem[88064];
    bf16* zt   = (bf16*)smem;                 // [32][64]  swizzled (4 KB)
    bf16* h1   = (bf16*)(smem + 4096);        // [32][512] swizzled (32 KB)
    bf16* at   = (bf16*)(smem + 36864);       // [32][512] swizzled (32 KB)
    bf16* h2   = (bf16*)(smem + 69632);       // [32][256] swizzled (16 KB)
    float* trp = (float*)(smem + 86016);      // [16][32]           (2 KB)
    float* vp  = (float*)smem;                // [8][32][64] overlays zt+h1+at

    const int tid  = threadIdx.x;
    const int wid  = tid >> 6;                // 0..15
    const int lane = tid & 63;
    const int r    = lane & 15;
    const int kq   = lane >> 4;
    const int rx   = r & 7;
    const int laneE = lane * 8;
    const int rt   = blockIdx.x >> 1;
    const int ch   = blockIdx.x & 1;
    const int bm   = rt * 32;

    // ---- preload biases before any asm loads; pin them live ----
    float bias1[2];
#pragma unroll
    for (int f = 0; f < 2; ++f) bias1[f] = b1eff[wid * 32 + f * 16 + r];
    float bias2 = b2[ch * 256 + wid * 16 + r];
    asm volatile("" :: "v"(bias1[0]), "v"(bias1[1]), "v"(bias2));

    // ---- stage z: 32x64 f32 -> bf16 swizzled (2 elems/thread) ----
    {
        int i = tid * 2;
        int row = i >> 6, col = i & 63;
        float2 v = *(const float2*)(z + (size_t)(bm + row) * DD + col);
        st_swz(zt, row, col,     64, v.x);
        st_swz(zt, row, col + 1, 64, v.y);
    }

    // ---- L1 prefetch: wave strip = 32 cols, 2 entries (K=64) ----
    short8 q0, q1, q2, q3, p0, p1;
    const bf16* Wb1 = W1p + (size_t)wid * 2048 + laneE;
    GLD2(q0, q1, Wb1);
    GLD2(p0, p1, Wb1 + 1024);
    LGKMBAR();    // zt visible; L1 weight loads stay in flight

    // ---- L1: h1 = tanh(z @ W1 + b1eff); a = 1-h1^2 (2 rowgroups) ----
    f32x4 acc1[2][2] = {};    // [g][f]
    WAITV(2);
#pragma unroll
    for (int g = 0; g < 2; ++g) {
        short8 av = *(const short8*)(zt + (g * 16 + r) * 64 + ((kq ^ rx) << 3));
        acc1[g][0] = __builtin_amdgcn_mfma_f32_16x16x32_bf16(av, q0, acc1[g][0], 0, 0, 0);
        acc1[g][1] = __builtin_amdgcn_mfma_f32_16x16x32_bf16(av, q1, acc1[g][1], 0, 0, 0);
    }
    WAITV(0);
#pragma unroll
    for (int g = 0; g < 2; ++g) {
        short8 av = *(const short8*)(zt + (g * 16 + r) * 64 + (((4 + kq) ^ rx) << 3));
        acc1[g][0] = __builtin_amdgcn_mfma_f32_16x16x32_bf16(av, p0, acc1[g][0], 0, 0, 0);
        acc1[g][1] = __builtin_amdgcn_mfma_f32_16x16x32_bf16(av, p1, acc1[g][1], 0, 0, 0);
    }
    // L1 epilogue
#pragma unroll
    for (int g = 0; g < 2; ++g)
#pragma unroll
        for (int f = 0; f < 2; ++f) {
            int col = wid * 32 + f * 16 + r;
#pragma unroll
            for (int v = 0; v < 4; ++v) {
                int row = g * 16 + kq * 4 + v;
                float h = tanh_fast(acc1[g][f][v] + bias1[f]);
                st_swz(h1, row, col, 512, h);
                st_swz(at, row, col, 512, fmaf(-h, h, 1.0f));
            }
        }
    LGKMBAR();    // h1/at visible

    // ---- merged L2 || E: REPS x 16-step loop (reps 0,1 = timing dummies) ----
    const bf16* Wb2 = W2p + (size_t)(ch * 16 + wid) * 8192 + laneE;
    const bf16* WbE = Pp  + (size_t)(ch * 16 + wid) * 8192 + laneE;
    f32x4 acc2[2] = {};   // h1 @ W2
    f32x4 accE[2] = {};   // at @ P
    short8 rbW[4], rbP[4];
#pragma unroll
    for (int rep = 0; rep < 3; ++rep) {
        // ring prologue: 3 pairs in flight
        GLD1(rbW[0], Wb2);        GLD1(rbP[0], WbE);
        GLD1(rbW[1], Wb2 + 512);  GLD1(rbP[1], WbE + 512);
        GLD1(rbW[2], Wb2 + 1024); GLD1(rbP[2], WbE + 1024);
#pragma unroll
        for (int s = 0; s < 16; ++s) {
            // hoisted A-fragment ds_reads (overlap the vmcnt stall)
            int co = (((s * 4 + kq) ^ rx) << 3);
            short8 a1v[2], aav[2];
#pragma unroll
            for (int g = 0; g < 2; ++g) {
                a1v[g] = *(const short8*)(h1 + (g * 16 + r) * 512 + co);
                aav[g] = *(const short8*)(at + (g * 16 + r) * 512 + co);
            }
            if (s + 3 < 16) {
                GLD1(rbW[(s + 3) & 3], Wb2 + (s + 3) * 512);
                GLD1(rbP[(s + 3) & 3], WbE + (s + 3) * 512);
                WAITV(6);
            } else if (s + 2 < 16) { WAITV(4); }
            else if (s + 1 < 16)   { WAITV(2); }
            else                   { WAITV(0); }
#pragma unroll
            for (int g = 0; g < 2; ++g) {
                acc2[g] = __builtin_amdgcn_mfma_f32_16x16x32_bf16(a1v[g], rbW[s & 3], acc2[g], 0, 0, 0);
                accE[g] = __builtin_amdgcn_mfma_f32_16x16x32_bf16(aav[g], rbP[s & 3], accE[g], 0, 0, 0);
            }
        }
        if (rep < 2) {
            // keep dummy results live (defeat DCE, rule 17), then reset
            asm volatile("" :: "v"(acc2[0]), "v"(acc2[1]),
                               "v"(accE[0]), "v"(accE[1]));
            acc2[0] = f32x4{}; acc2[1] = f32x4{};
            accE[0] = f32x4{}; accE[1] = f32x4{};
        }
    }
    // epilogue: h2 + bsq from acc2; L3 prefetch; trace from accE*bsq
    f32x4 bsq[2];
    {
        int colL = wid * 16 + r;
#pragma unroll
        for (int g = 0; g < 2; ++g)
#pragma unroll
            for (int v = 0; v < 4; ++v) {
                int row = g * 16 + kq * 4 + v;
                float h = tanh_fast(acc2[g][v] + bias2);
                st_swz(h2, row, colL, 256, h);
                bsq[g][v] = fmaf(-h, h, 1.0f);
            }
        const int kw = wid & 7;
        const bf16* Wb3 = W3p + (size_t)(ch * 8 + kw) * 2048 + laneE;
        GLD4(q0, q1, q2, q3, Wb3);
#pragma unroll
        for (int g = 0; g < 2; ++g)
#pragma unroll
            for (int v = 0; v < 4; ++v) {
                float p = accE[g][v] * bsq[g][v];
                p += __shfl_xor(p, 1);
                p += __shfl_xor(p, 2);
                p += __shfl_xor(p, 4);
                p += __shfl_xor(p, 8);
                if (r == 0) trp[wid * 32 + g * 16 + kq * 4 + v] = p;
            }
    }
    LGKMBAR();    // h2/trp visible; h1/at reads done -> vp overlay safe

    // ---- L3: v-partial = h2 @ W3 (this half's k); 8 kw x 2 row-halves ----
    {
        const int kw = wid & 7, rp = wid >> 3;
        f32x4 c0 = {}, c1 = {}, c2 = {}, c3 = {};
        short8 av = *(const short8*)(h2 + (rp * 16 + r) * 256 + (((kw * 4 + kq) ^ rx) << 3));
        WAITV(0);
        c0 = __builtin_amdgcn_mfma_f32_16x16x32_bf16(av, q0, c0, 0, 0, 0);
        c1 = __builtin_amdgcn_mfma_f32_16x16x32_bf16(av, q1, c1, 0, 0, 0);
        c2 = __builtin_amdgcn_mfma_f32_16x16x32_bf16(av, q2, c2, 0, 0, 0);
        c3 = __builtin_amdgcn_mfma_f32_16x16x32_bf16(av, q3, c3, 0, 0, 0);
#pragma unroll
        for (int v = 0; v < 4; ++v) {
            int row = rp * 16 + kq * 4 + v;
            vp[kw * 2048 + row * 64 + 0 * 16 + r] = c0[v];
            vp[kw * 2048 + row * 64 + 1 * 16 + r] = c1[v];
            vp[kw * 2048 + row * 64 + 2 * 16 + r] = c2[v];
            vp[kw * 2048 + row * 64 + 3 * 16 + r] = c3[v];
        }
    }
    LGKMBAR();

    // ---- final: reduce 8 k-chunk partials; atomicAdd v and trace ----
#pragma unroll
    for (int it = 0; it < 2; ++it) {
        int i = it * 1024 + tid;
        int row = i >> 6, col = i & 63;
        float s = 0.f;
#pragma unroll
        for (int kw = 0; kw < 8; ++kw) s += vp[kw * 2048 + i];
        atomicAdd(outV + (size_t)(bm + row) * DD + col, s);
    }
    if (tid < 32) {
        float s = 0.f;
#pragma unroll
        for (int w = 0; w < 16; ++w) s += trp[w * 32 + tid];
        atomicAdd(outTr + bm + tid, -s);
    }
}

extern "C" void kernel_launch(void* const* d_in, const int* in_sizes, int n_in,
                              void* d_out, int out_size, void* d_ws, size_t ws_size,
                              hipStream_t stream)
{
    const float* z  = (const float*)d_in[0];
    const float* t  = (const float*)d_in[2];
    const float* W1 = (const float*)d_in[3];
    const float* b1 = (const float*)d_in[4];
    const float* W2 = (const float*)d_in[5];
    const float* b2 = (const float*)d_in[6];
    const float* W3 = (const float*)d_in[7];
    const float* b3 = (const float*)d_in[8];
    float* out = (float*)d_out;                 // v [4096*64] then dlogp [4096]
    float* out_tr = out + (size_t)BB * DD;

    char* w = (char*)d_ws;
    auto alloc = [&](size_t bytes) {
        char* p = w;
        w += (bytes + 255) & ~(size_t)255;
        return p;
    };
    bf16* W1p   = (bf16*)alloc((size_t)64  * 512 * 2);
    bf16* W2p   = (bf16*)alloc((size_t)512 * 512 * 2);
    bf16* W3p   = (bf16*)alloc((size_t)64  * 512 * 2);
    bf16* Pp    = (bf16*)alloc((size_t)512 * 512 * 2);
    float* b1eff = (float*)alloc((size_t)HH * 4);

    // prep: packs + P + b1eff + output init (v=b3 broadcast, trace=0)
    prep_kernel<<<549, 256, 0, stream>>>(t, W1, b1, W2, W3, b3,
                                         W1p, W2p, W3p, Pp, b1eff, out);
    fused_rows<<<128 * 2, 1024, 0, stream>>>(z, W1p, W2p, W3p, Pp,
                                             b1eff, b2, out, out_tr);
}

// Round 15
// 29.474 us; speedup vs baseline: 1.7945x; 1.7945x over previous
//
#include <hip/hip_runtime.h>
#include <hip/hip_bf16.h>

#define BB 4096   // batch
#define DD 64     // event dim
#define HH 512    // hidden

typedef short short8 __attribute__((ext_vector_type(8)));   // 8 bf16
typedef float f32x4  __attribute__((ext_vector_type(4)));
typedef __hip_bfloat16 bf16;

// branchless fast tanh: 1 - 2/(1+e^{2x}); exact limits at +-inf
__device__ __forceinline__ float tanh_fast(float x) {
    float e = __expf(2.0f * x);
    return 1.0f - __fdividef(2.0f, 1.0f + e);
}

// pack two floats to bf16x2 (lo in low half)
__device__ __forceinline__ unsigned pk2(float lo, float hi) {
    return (unsigned)__bfloat16_as_ushort(__float2bfloat16(lo)) |
           ((unsigned)__bfloat16_as_ushort(__float2bfloat16(hi)) << 16);
}

// swizzled LDS bf16-PAIR store (col even, col&7<7): one b32 write
__device__ __forceinline__ void st_swz32(bf16* base, int row, int col, int rs, unsigned v) {
    int e = row * rs + ((((col >> 3) ^ (row & 7))) << 3) + (col & 7);
    *(unsigned*)(base + e) = v;
}

// single 1KB fragment load (proven R10/R12)
#define GLD1(dst, addr)                                                      \
  asm volatile("global_load_dwordx4 %0, %1, off" : "=&v"(dst) : "v"(addr))

// 2KB entry = 2 x 1KB
#define GLD2(e0, e1, addr)                                                   \
  asm volatile("global_load_dwordx4 %0, %2, off\n\t"                         \
               "global_load_dwordx4 %1, %2, off offset:1024"                 \
               : "=&v"(e0), "=&v"(e1) : "v"(addr))

// 4KB entry = 4 x 1KB
#define GLD4(e0, e1, e2, e3, addr)                                           \
  asm volatile("global_load_dwordx4 %0, %4, off\n\t"                         \
               "global_load_dwordx4 %1, %4, off offset:1024\n\t"             \
               "global_load_dwordx4 %2, %4, off offset:2048\n\t"             \
               "global_load_dwordx4 %3, %4, off offset:3072"                 \
               : "=&v"(e0), "=&v"(e1), "=&v"(e2), "=&v"(e3) : "v"(addr))

// counted wait + compiler motion fence (rule 18)
#define WAITV(n)                                                             \
  do { asm volatile("s_waitcnt vmcnt(" #n ")" ::: "memory");                 \
       __builtin_amdgcn_sched_barrier(0); } while (0)

// LDS-only barrier: raw s_barrier with lgkmcnt drain but NO vmcnt drain
#define LGKMBAR()                                                            \
  do { asm volatile("s_waitcnt lgkmcnt(0)" ::: "memory");                    \
       __builtin_amdgcn_s_barrier();                                         \
       __builtin_amdgcn_sched_barrier(0); } while (0)

// ===========================================================================
// Packed weights (16-col x 32-k tiles, tile = 512 elems = 1KB; lane l:
// kq=l>>4, r=l&15 owns B[col=base+r][k=kbase+kq*8+j], j=0..7 = 16B).
//   W1p: T = w*4 + s*2 + f   (w 0..15, s 0..1, f 0..1)  col=(w*2+f)*16+r
//   W2p: T = cw*16 + s       (cw 0..31, s 0..15)        col=cw*16+r
//   Pp : T = cw*16 + s       outcol k=cw*16+r, reduce j=s*32+kq*8+jj
//   W3p: T = q*4 + f         (q 0..15, f 0..3)          col=f*16+r, k=q*32+..
// ===========================================================================
__global__ __launch_bounds__(256) void prep_kernel(
    const float* __restrict__ t, const float* __restrict__ W1,
    const float* __restrict__ b1, const float* __restrict__ W2,
    const float* __restrict__ W3,
    bf16* __restrict__ W1p, bf16* __restrict__ W2p, bf16* __restrict__ W3p,
    bf16* __restrict__ Pp, float* __restrict__ b1eff)
{
    const int tid  = threadIdx.x;
    const int bx   = blockIdx.x;
    const int lane = tid & 63;
    const int r    = lane & 15;
    const int kq   = lane >> 4;

    if (bx < 160) {
        int T = bx * 4 + (tid >> 6);     // 0..639
        const float* src;
        bf16* dst;
        int stride;
        if (T < 64) {            // W1p
            int w = T >> 2, s = (T >> 1) & 1, f = T & 1;
            src = W1 + (size_t)(s * 32 + kq * 8) * HH + (w * 2 + f) * 16 + r;
            stride = HH;
            dst = W1p + (size_t)T * 512 + lane * 8;
        } else if (T < 576) {    // W2p
            int tt = T - 64;
            int cw = tt >> 4, s = tt & 15;
            src = W2 + (size_t)(s * 32 + kq * 8) * HH + cw * 16 + r;
            stride = HH;
            dst = W2p + (size_t)tt * 512 + lane * 8;
        } else {                 // W3p
            int tt = T - 576;
            int q = tt >> 2, f = tt & 3;
            src = W3 + (size_t)(q * 32 + kq * 8) * DD + f * 16 + r;
            stride = DD;
            dst = W3p + (size_t)tt * 512 + lane * 8;
        }
        short8 v;
#pragma unroll
        for (int j = 0; j < 8; ++j)
            v[j] = (short)__bfloat16_as_ushort(__float2bfloat16(src[(size_t)j * stride]));
        *(short8*)dst = v;
    } else if (bx < 288) {
        // Pp tile pt: out-col k = cw*16+r, reduce j = s*32+kq*8+jj
        int pt = (bx - 160) * 4 + (tid >> 6);    // 0..511
        int cw = pt >> 4, s = pt & 15;
        int k  = cw * 16 + r;
        int j0 = s * 32 + kq * 8;
        float acc[8] = {};
        const float* w3row = W3 + (size_t)k * DD;
        for (int d = 0; d < DD; ++d) {
            float w3 = w3row[d];
            const float4* w1p4 = (const float4*)(W1 + (size_t)d * HH + j0);
            float4 x = w1p4[0], y = w1p4[1];
            acc[0] += x.x * w3; acc[1] += x.y * w3;
            acc[2] += x.z * w3; acc[3] += x.w * w3;
            acc[4] += y.x * w3; acc[5] += y.y * w3;
            acc[6] += y.z * w3; acc[7] += y.w * w3;
        }
        short8 v;
#pragma unroll
        for (int j = 0; j < 8; ++j)
            v[j] = (short)__bfloat16_as_ushort(
                __float2bfloat16(acc[j] * W2[(size_t)(j0 + j) * HH + k]));
        *(short8*)(Pp + (size_t)pt * 512 + lane * 8) = v;
    } else {
        float tv = t[0];
        b1eff[tid]       = b1[tid]       + tv * W1[(size_t)64 * HH + tid];
        b1eff[tid + 256] = b1[tid + 256] + tv * W1[(size_t)64 * HH + tid + 256];
    }
}

// ---------------------------------------------------------------------------
// fused_rows: 256 blocks x 1024 threads (16 waves). bid = rt*2 + ch:
// 32 batch rows (rt), column-half ch. L1 -> [L2||E merged loop, dual
// 5-slot/4-ahead asm rings, counted vmcnt] -> L3. All LDS stores packed
// to b32 (bank-clean); vp padded stride 68. Outputs: per-ch PARTIAL
// buffers (plain coalesced stores, no atomics); reduce_out combines.
// ---------------------------------------------------------------------------
__global__ __launch_bounds__(1024, 2) void fused_rows(
    const float* __restrict__ z, const bf16* __restrict__ W1p,
    const bf16* __restrict__ W2p, const bf16* __restrict__ W3p,
    const bf16* __restrict__ Pp, const float* __restrict__ b1eff,
    const float* __restrict__ b2,
    float* __restrict__ vpart, float* __restrict__ tpart)
{
    __shared__ alignas(16) char smem[88064];
    bf16* zt   = (bf16*)smem;                 // [32][64]  swizzled (4 KB)
    bf16* h1   = (bf16*)(smem + 4096);        // [32][512] swizzled (32 KB)
    bf16* at   = (bf16*)(smem + 36864);       // [32][512] swizzled (32 KB)
    bf16* h2   = (bf16*)(smem + 69632);       // [32][256] swizzled (16 KB)
    float* trp = (float*)(smem + 86016);      // [16][32]           (2 KB)
    float* vp  = (float*)smem;                // [8][32][68] pad68, overlays zt+h1+at

    const int tid  = threadIdx.x;
    const int wid  = tid >> 6;                // 0..15
    const int lane = tid & 63;
    const int r    = lane & 15;
    const int kq   = lane >> 4;
    const int rx   = r & 7;
    const int laneE = lane * 8;
    const int rt   = blockIdx.x >> 1;
    const int ch   = blockIdx.x & 1;
    const int bm   = rt * 32;
    float* myV = vpart + (size_t)ch * (BB * DD);
    float* myT = tpart + (size_t)ch * BB;

    // ---- preload biases before any asm loads; pin them live ----
    float bias1[2];
#pragma unroll
    for (int f = 0; f < 2; ++f) bias1[f] = b1eff[wid * 32 + f * 16 + r];
    float bias2 = b2[ch * 256 + wid * 16 + r];
    asm volatile("" :: "v"(bias1[0]), "v"(bias1[1]), "v"(bias2));

    // ---- stage z: 32x64 f32 -> bf16 swizzled, ONE b32 per thread ----
    {
        int i = tid * 2;
        int row = i >> 6, col = i & 63;
        float2 v = *(const float2*)(z + (size_t)(bm + row) * DD + col);
        st_swz32(zt, row, col, 64, pk2(v.x, v.y));
    }

    // ---- L1 prefetch: wave strip = 32 cols, 2 entries (K=64) ----
    short8 q0, q1, q2, q3, p0, p1;
    const bf16* Wb1 = W1p + (size_t)wid * 2048 + laneE;
    GLD2(q0, q1, Wb1);
    GLD2(p0, p1, Wb1 + 1024);
    LGKMBAR();    // zt visible; L1 weight loads stay in flight

    // ---- L1: h1 = tanh(z @ W1 + b1eff); a = 1-h1^2 (2 rowgroups) ----
    f32x4 acc1[2][2] = {};    // [g][f]
    WAITV(2);
#pragma unroll
    for (int g = 0; g < 2; ++g) {
        short8 av = *(const short8*)(zt + (g * 16 + r) * 64 + ((kq ^ rx) << 3));
        acc1[g][0] = __builtin_amdgcn_mfma_f32_16x16x32_bf16(av, q0, acc1[g][0], 0, 0, 0);
        acc1[g][1] = __builtin_amdgcn_mfma_f32_16x16x32_bf16(av, q1, acc1[g][1], 0, 0, 0);
    }
    WAITV(0);
#pragma unroll
    for (int g = 0; g < 2; ++g) {
        short8 av = *(const short8*)(zt + (g * 16 + r) * 64 + (((4 + kq) ^ rx) << 3));
        acc1[g][0] = __builtin_amdgcn_mfma_f32_16x16x32_bf16(av, p0, acc1[g][0], 0, 0, 0);
        acc1[g][1] = __builtin_amdgcn_mfma_f32_16x16x32_bf16(av, p1, acc1[g][1], 0, 0, 0);
    }
    // merged-loop prologue: 4 pairs (W2,Pp) = 8 loads in flight
    short8 rbW[5], rbP[5];
    const bf16* Wb2 = W2p + (size_t)(ch * 16 + wid) * 8192 + laneE;
    const bf16* WbE = Pp  + (size_t)(ch * 16 + wid) * 8192 + laneE;
    GLD1(rbW[0], Wb2);        GLD1(rbP[0], WbE);
    GLD1(rbW[1], Wb2 + 512);  GLD1(rbP[1], WbE + 512);
    GLD1(rbW[2], Wb2 + 1024); GLD1(rbP[2], WbE + 1024);
    GLD1(rbW[3], Wb2 + 1536); GLD1(rbP[3], WbE + 1536);
    // L1 epilogue: packed b32 stores (even lanes store own+neighbor col)
#pragma unroll
    for (int g = 0; g < 2; ++g)
#pragma unroll
        for (int f = 0; f < 2; ++f) {
            int col = wid * 32 + f * 16 + r;
#pragma unroll
            for (int v = 0; v < 4; ++v) {
                int row = g * 16 + kq * 4 + v;
                float h = tanh_fast(acc1[g][f][v] + bias1[f]);
                float a = fmaf(-h, h, 1.0f);
                float ho = __shfl_xor(h, 1);
                float ao = __shfl_xor(a, 1);
                if (!(r & 1)) {
                    st_swz32(h1, row, col, 512, pk2(h, ho));
                    st_swz32(at, row, col, 512, pk2(a, ao));
                }
            }
        }
    LGKMBAR();    // h1/at visible; ring loads stay in flight

    // ---- merged L2 || E: one 16-step loop, 4-ahead/5-slot rings ----
    f32x4 acc2[2] = {};   // h1 @ W2
    f32x4 accE[2] = {};   // at @ P
#pragma unroll
    for (int s = 0; s < 16; ++s) {
        // hoisted A-fragment ds_reads (overlap the vmcnt stall)
        int co = (((s * 4 + kq) ^ rx) << 3);
        short8 a1v[2], aav[2];
#pragma unroll
        for (int g = 0; g < 2; ++g) {
            a1v[g] = *(const short8*)(h1 + (g * 16 + r) * 512 + co);
            aav[g] = *(const short8*)(at + (g * 16 + r) * 512 + co);
        }
        if (s + 4 < 16) {
            GLD1(rbW[(s + 4) % 5], Wb2 + (s + 4) * 512);
            GLD1(rbP[(s + 4) % 5], WbE + (s + 4) * 512);
            WAITV(8);
        } else if (s + 3 < 16) { WAITV(6); }
        else if (s + 2 < 16)   { WAITV(4); }
        else if (s + 1 < 16)   { WAITV(2); }
        else                   { WAITV(0); }
#pragma unroll
        for (int g = 0; g < 2; ++g) {
            acc2[g] = __builtin_amdgcn_mfma_f32_16x16x32_bf16(a1v[g], rbW[s % 5], acc2[g], 0, 0, 0);
            accE[g] = __builtin_amdgcn_mfma_f32_16x16x32_bf16(aav[g], rbP[s % 5], accE[g], 0, 0, 0);
        }
    }
    // epilogue: h2 (packed stores) + bsq; L3 prefetch; trace partials
    f32x4 bsq[2];
    {
        int colL = wid * 16 + r;
#pragma unroll
        for (int g = 0; g < 2; ++g)
#pragma unroll
            for (int v = 0; v < 4; ++v) {
                int row = g * 16 + kq * 4 + v;
                float h = tanh_fast(acc2[g][v] + bias2);
                bsq[g][v] = fmaf(-h, h, 1.0f);
                float ho = __shfl_xor(h, 1);
                if (!(r & 1)) st_swz32(h2, row, colL, 256, pk2(h, ho));
            }
        const int kw = wid & 7;
        const bf16* Wb3 = W3p + (size_t)(ch * 8 + kw) * 2048 + laneE;
        GLD4(q0, q1, q2, q3, Wb3);
#pragma unroll
        for (int g = 0; g < 2; ++g)
#pragma unroll
            for (int v = 0; v < 4; ++v) {
                float p = accE[g][v] * bsq[g][v];
                p += __shfl_xor(p, 1);
                p += __shfl_xor(p, 2);
                p += __shfl_xor(p, 4);
                p += __shfl_xor(p, 8);
                if (r == 0) trp[wid * 32 + g * 16 + kq * 4 + v] = p;
            }
    }
    LGKMBAR();    // h2/trp visible; h1/at reads done -> vp overlay safe

    // ---- L3: v-partial = h2 @ W3 (this half's k); 8 kw x 2 row-halves ----
    {
        const int kw = wid & 7, rp = wid >> 3;
        f32x4 c0 = {}, c1 = {}, c2 = {}, c3 = {};
        short8 av = *(const short8*)(h2 + (rp * 16 + r) * 256 + (((kw * 4 + kq) ^ rx) << 3));
        WAITV(0);
        c0 = __builtin_amdgcn_mfma_f32_16x16x32_bf16(av, q0, c0, 0, 0, 0);
        c1 = __builtin_amdgcn_mfma_f32_16x16x32_bf16(av, q1, c1, 0, 0, 0);
        c2 = __builtin_amdgcn_mfma_f32_16x16x32_bf16(av, q2, c2, 0, 0, 0);
        c3 = __builtin_amdgcn_mfma_f32_16x16x32_bf16(av, q3, c3, 0, 0, 0);
#pragma unroll
        for (int v = 0; v < 4; ++v) {
            int row = rp * 16 + kq * 4 + v;
            vp[kw * 2176 + row * 68 + 0 * 16 + r] = c0[v];
            vp[kw * 2176 + row * 68 + 1 * 16 + r] = c1[v];
            vp[kw * 2176 + row * 68 + 2 * 16 + r] = c2[v];
            vp[kw * 2176 + row * 68 + 3 * 16 + r] = c3[v];
        }
    }
    LGKMBAR();

    // ---- final: reduce 8 k-chunk partials; PLAIN stores to partials ----
#pragma unroll
    for (int it = 0; it < 2; ++it) {
        int i = it * 1024 + tid;
        int row = i >> 6, col = i & 63;
        float s = 0.f;
#pragma unroll
        for (int kw = 0; kw < 8; ++kw) s += vp[kw * 2176 + row * 68 + col];
        myV[(size_t)(bm + row) * DD + col] = s;
    }
    if (tid < 32) {
        float s = 0.f;
#pragma unroll
        for (int w = 0; w < 16; ++w) s += trp[w * 32 + tid];
        myT[bm + tid] = -s;
    }
}

// ---------------------------------------------------------------------------
// reduce_out: out_v = vpart0 + vpart1 + b3; out_tr = tpart0 + tpart1.
// 260 blocks x 256 threads, float4 each (65536 v-quads + 1024 tr-quads).
// ---------------------------------------------------------------------------
__global__ __launch_bounds__(256) void reduce_out(
    const float* __restrict__ vpart, const float* __restrict__ tpart,
    const float* __restrict__ b3, float* __restrict__ out)
{
    int idx = blockIdx.x * 256 + threadIdx.x;
    if (idx < 65536) {
        float4 a = ((const float4*)vpart)[idx];
        float4 b = ((const float4*)(vpart + BB * DD))[idx];
        float4 c = *(const float4*)(b3 + ((idx * 4) & 63));
        float4 s = make_float4(a.x + b.x + c.x, a.y + b.y + c.y,
                               a.z + b.z + c.z, a.w + b.w + c.w);
        ((float4*)out)[idx] = s;
    } else {
        int i = idx - 65536;     // 0..1023
        float4 a = ((const float4*)tpart)[i];
        float4 b = ((const float4*)(tpart + BB))[i];
        float4 s = make_float4(a.x + b.x, a.y + b.y, a.z + b.z, a.w + b.w);
        ((float4*)(out + BB * DD))[i] = s;
    }
}

extern "C" void kernel_launch(void* const* d_in, const int* in_sizes, int n_in,
                              void* d_out, int out_size, void* d_ws, size_t ws_size,
                              hipStream_t stream)
{
    const float* z  = (const float*)d_in[0];
    const float* t  = (const float*)d_in[2];
    const float* W1 = (const float*)d_in[3];
    const float* b1 = (const float*)d_in[4];
    const float* W2 = (const float*)d_in[5];
    const float* b2 = (const float*)d_in[6];
    const float* W3 = (const float*)d_in[7];
    const float* b3 = (const float*)d_in[8];
    float* out = (float*)d_out;                 // v [4096*64] then dlogp [4096]

    char* w = (char*)d_ws;
    auto alloc = [&](size_t bytes) {
        char* p = w;
        w += (bytes + 255) & ~(size_t)255;
        return p;
    };
    bf16* W1p   = (bf16*)alloc((size_t)64  * 512 * 2);
    bf16* W2p   = (bf16*)alloc((size_t)512 * 512 * 2);
    bf16* W3p   = (bf16*)alloc((size_t)64  * 512 * 2);
    bf16* Pp    = (bf16*)alloc((size_t)512 * 512 * 2);
    float* b1eff = (float*)alloc((size_t)HH * 4);
    float* vpart = (float*)alloc((size_t)2 * BB * DD * 4);   // per-ch v partials
    float* tpart = (float*)alloc((size_t)2 * BB * 4);        // per-ch tr partials

    prep_kernel<<<289, 256, 0, stream>>>(t, W1, b1, W2, W3,
                                         W1p, W2p, W3p, Pp, b1eff);
    fused_rows<<<128 * 2, 1024, 0, stream>>>(z, W1p, W2p, W3p, Pp,
                                             b1eff, b2, vpart, tpart);
    reduce_out<<<260, 256, 0, stream>>>(vpart, tpart, b3, out);
}

// Round 16
// 23.609 us; speedup vs baseline: 2.2404x; 1.2484x over previous
//
#include <hip/hip_runtime.h>
#include <hip/hip_bf16.h>

#define BB 4096   // batch
#define DD 64     // event dim
#define HH 512    // hidden

typedef short short8 __attribute__((ext_vector_type(8)));   // 8 bf16
typedef float f32x4  __attribute__((ext_vector_type(4)));
typedef __hip_bfloat16 bf16;

// branchless fast tanh: 1 - 2/(1+e^{2x}); exact limits at +-inf
__device__ __forceinline__ float tanh_fast(float x) {
    float e = __expf(2.0f * x);
    return 1.0f - __fdividef(2.0f, 1.0f + e);
}

// swizzled LDS bf16 store: 8-elem chunk XOR'd with row&7 (write side)
__device__ __forceinline__ void st_swz(bf16* base, int row, int col, int rs, float v) {
    base[row * rs + ((((col >> 3) ^ (row & 7))) << 3) + (col & 7)] = __float2bfloat16(v);
}

// single 1KB fragment load (proven R10/R12)
#define GLD1(dst, addr)                                                      \
  asm volatile("global_load_dwordx4 %0, %1, off" : "=&v"(dst) : "v"(addr))

// 2KB entry = 2 x 1KB
#define GLD2(e0, e1, addr)                                                   \
  asm volatile("global_load_dwordx4 %0, %2, off\n\t"                         \
               "global_load_dwordx4 %1, %2, off offset:1024"                 \
               : "=&v"(e0), "=&v"(e1) : "v"(addr))

// 4KB entry = 4 x 1KB
#define GLD4(e0, e1, e2, e3, addr)                                           \
  asm volatile("global_load_dwordx4 %0, %4, off\n\t"                         \
               "global_load_dwordx4 %1, %4, off offset:1024\n\t"             \
               "global_load_dwordx4 %2, %4, off offset:2048\n\t"             \
               "global_load_dwordx4 %3, %4, off offset:3072"                 \
               : "=&v"(e0), "=&v"(e1), "=&v"(e2), "=&v"(e3) : "v"(addr))

// counted wait + compiler motion fence (rule 18)
#define WAITV(n)                                                             \
  do { asm volatile("s_waitcnt vmcnt(" #n ")" ::: "memory");                 \
       __builtin_amdgcn_sched_barrier(0); } while (0)

// LDS-only barrier: raw s_barrier with lgkmcnt drain but NO vmcnt drain
#define LGKMBAR()                                                            \
  do { asm volatile("s_waitcnt lgkmcnt(0)" ::: "memory");                    \
       __builtin_amdgcn_s_barrier();                                         \
       __builtin_amdgcn_sched_barrier(0); } while (0)

// ===========================================================================
// Packed weights (16-col x 32-k tiles, tile = 512 elems = 1KB; lane l:
// kq=l>>4, r=l&15 owns B[col=base+r][k=kbase+kq*8+j], j=0..7 = 16B).
//   W1p: T = w*4 + s*2 + f   (w 0..15, s 0..1, f 0..1)  col=(w*2+f)*16+r
//   W2p: T = cw*16 + s       (cw 0..31, s 0..15)        col=cw*16+r
//   Pp : T = cw*16 + s       outcol k=cw*16+r, reduce j=s*32+kq*8+jj
//   W3p: T = q*4 + f         (q 0..15, f 0..3)          col=f*16+r, k=q*32+..
//
// Grid (933 blocks x 256):
//   [0,160)    pack W1p/W2p/W3p (4 tiles/block)
//   [160,672)  Pp: ONE tile per block, 4 waves split d-reduction 4-ways
//   672        b1eff
//   [673,933)  output init (v = b3 broadcast, trace = 0)
// ===========================================================================
__global__ __launch_bounds__(256) void prep_kernel(
    const float* __restrict__ t, const float* __restrict__ W1,
    const float* __restrict__ b1, const float* __restrict__ W2,
    const float* __restrict__ W3, const float* __restrict__ b3,
    bf16* __restrict__ W1p, bf16* __restrict__ W2p, bf16* __restrict__ W3p,
    bf16* __restrict__ Pp, float* __restrict__ b1eff, float* __restrict__ out)
{
    const int tid  = threadIdx.x;
    const int bx   = blockIdx.x;
    const int lane = tid & 63;
    const int r    = lane & 15;
    const int kq   = lane >> 4;

    if (bx < 160) {
        int T = bx * 4 + (tid >> 6);     // 0..639
        const float* src;
        bf16* dst;
        int stride;
        if (T < 64) {            // W1p
            int w = T >> 2, s = (T >> 1) & 1, f = T & 1;
            src = W1 + (size_t)(s * 32 + kq * 8) * HH + (w * 2 + f) * 16 + r;
            stride = HH;
            dst = W1p + (size_t)T * 512 + lane * 8;
        } else if (T < 576) {    // W2p
            int tt = T - 64;
            int cw = tt >> 4, s = tt & 15;
            src = W2 + (size_t)(s * 32 + kq * 8) * HH + cw * 16 + r;
            stride = HH;
            dst = W2p + (size_t)tt * 512 + lane * 8;
        } else {                 // W3p
            int tt = T - 576;
            int q = tt >> 2, f = tt & 3;
            src = W3 + (size_t)(q * 32 + kq * 8) * DD + f * 16 + r;
            stride = DD;
            dst = W3p + (size_t)tt * 512 + lane * 8;
        }
        short8 v;
#pragma unroll
        for (int j = 0; j < 8; ++j)
            v[j] = (short)__bfloat16_as_ushort(__float2bfloat16(src[(size_t)j * stride]));
        *(short8*)dst = v;
    } else if (bx < 672) {
        // Pp tile pt (one per block): out-col k = cw*16+r, reduce j = s*32+kq*8+jj
        // 4 waves: wave wq covers d in [wq*16, wq*16+16); LDS partial reduce.
        __shared__ float part[4][64][8];
        int pt = bx - 160;                       // 0..511
        int cw = pt >> 4, s = pt & 15;
        int k  = cw * 16 + r;
        int j0 = s * 32 + kq * 8;
        int wq = tid >> 6;
        float acc[8] = {};
        const float* w3row = W3 + (size_t)k * DD + wq * 16;
        const float* w1base = W1 + (size_t)(wq * 16) * HH + j0;
#pragma unroll
        for (int d = 0; d < 16; ++d) {
            float w3 = w3row[d];
            const float4* w1p4 = (const float4*)(w1base + (size_t)d * HH);
            float4 x = w1p4[0], y = w1p4[1];
            acc[0] += x.x * w3; acc[1] += x.y * w3;
            acc[2] += x.z * w3; acc[3] += x.w * w3;
            acc[4] += y.x * w3; acc[5] += y.y * w3;
            acc[6] += y.z * w3; acc[7] += y.w * w3;
        }
        *(f32x4*)&part[wq][lane][0] = *(f32x4*)&acc[0];
        *(f32x4*)&part[wq][lane][4] = *(f32x4*)&acc[4];
        __syncthreads();
        if (wq == 0) {
            short8 v;
#pragma unroll
            for (int j = 0; j < 8; ++j) {
                float ssum = part[0][lane][j] + part[1][lane][j] +
                             part[2][lane][j] + part[3][lane][j];
                v[j] = (short)__bfloat16_as_ushort(
                    __float2bfloat16(ssum * W2[(size_t)(j0 + j) * HH + k]));
            }
            *(short8*)(Pp + (size_t)pt * 512 + lane * 8) = v;
        }
    } else if (bx == 672) {
        float tv = t[0];
        b1eff[tid]       = b1[tid]       + tv * W1[(size_t)64 * HH + tid];
        b1eff[tid + 256] = b1[tid + 256] + tv * W1[(size_t)64 * HH + tid + 256];
    } else {
        // init output: v region = b3 broadcast, trace region = 0
        int idx = (bx - 673) * 1024 + tid * 4;   // 260 blocks, exact cover
        if (idx < BB * DD) {
            int col = idx & 63;
            *(float4*)(out + idx) =
                make_float4(b3[col], b3[col + 1], b3[col + 2], b3[col + 3]);
        } else {
            *(float4*)(out + idx) = make_float4(0.f, 0.f, 0.f, 0.f);
        }
    }
}

// ---------------------------------------------------------------------------
// fused_rows: BYTE-IDENTICAL to round-13 best (26.57us). 256 blocks x 1024
// threads (16 waves). bid = rt*2 + ch: 32 batch rows (rt), column-half ch.
// L1 -> [L2||E merged, dual 4-slot/3-ahead asm rings, counted vmcnt] -> L3.
// Barriers: raw s_barrier + lgkmcnt(0) (prefetches survive). v/trace via
// fp32 atomicAdd onto prep-initialized out.
// ---------------------------------------------------------------------------
__global__ __launch_bounds__(1024, 2) void fused_rows(
    const float* __restrict__ z, const bf16* __restrict__ W1p,
    const bf16* __restrict__ W2p, const bf16* __restrict__ W3p,
    const bf16* __restrict__ Pp, const float* __restrict__ b1eff,
    const float* __restrict__ b2,
    float* __restrict__ outV, float* __restrict__ outTr)
{
    __shared__ alignas(16) char smem[88064];
    bf16* zt   = (bf16*)smem;                 // [32][64]  swizzled (4 KB)
    bf16* h1   = (bf16*)(smem + 4096);        // [32][512] swizzled (32 KB)
    bf16* at   = (bf16*)(smem + 36864);       // [32][512] swizzled (32 KB)
    bf16* h2   = (bf16*)(smem + 69632);       // [32][256] swizzled (16 KB)
    float* trp = (float*)(smem + 86016);      // [16][32]           (2 KB)
    float* vp  = (float*)smem;                // [8][32][64] overlays zt+h1+at

    const int tid  = threadIdx.x;
    const int wid  = tid >> 6;                // 0..15
    const int lane = tid & 63;
    const int r    = lane & 15;
    const int kq   = lane >> 4;
    const int rx   = r & 7;
    const int laneE = lane * 8;
    const int rt   = blockIdx.x >> 1;
    const int ch   = blockIdx.x & 1;
    const int bm   = rt * 32;

    // ---- preload biases before any asm loads; pin them live ----
    float bias1[2];
#pragma unroll
    for (int f = 0; f < 2; ++f) bias1[f] = b1eff[wid * 32 + f * 16 + r];
    float bias2 = b2[ch * 256 + wid * 16 + r];
    asm volatile("" :: "v"(bias1[0]), "v"(bias1[1]), "v"(bias2));

    // ---- stage z: 32x64 f32 -> bf16 swizzled (2 elems/thread) ----
    {
        int i = tid * 2;
        int row = i >> 6, col = i & 63;
        float2 v = *(const float2*)(z + (size_t)(bm + row) * DD + col);
        st_swz(zt, row, col,     64, v.x);
        st_swz(zt, row, col + 1, 64, v.y);
    }

    // ---- L1 prefetch: wave strip = 32 cols, 2 entries (K=64) ----
    short8 q0, q1, q2, q3, p0, p1;
    const bf16* Wb1 = W1p + (size_t)wid * 2048 + laneE;
    GLD2(q0, q1, Wb1);
    GLD2(p0, p1, Wb1 + 1024);
    LGKMBAR();    // zt visible; L1 weight loads stay in flight

    // ---- L1: h1 = tanh(z @ W1 + b1eff); a = 1-h1^2 (2 rowgroups) ----
    f32x4 acc1[2][2] = {};    // [g][f]
    WAITV(2);
#pragma unroll
    for (int g = 0; g < 2; ++g) {
        short8 av = *(const short8*)(zt + (g * 16 + r) * 64 + ((kq ^ rx) << 3));
        acc1[g][0] = __builtin_amdgcn_mfma_f32_16x16x32_bf16(av, q0, acc1[g][0], 0, 0, 0);
        acc1[g][1] = __builtin_amdgcn_mfma_f32_16x16x32_bf16(av, q1, acc1[g][1], 0, 0, 0);
    }
    WAITV(0);
#pragma unroll
    for (int g = 0; g < 2; ++g) {
        short8 av = *(const short8*)(zt + (g * 16 + r) * 64 + (((4 + kq) ^ rx) << 3));
        acc1[g][0] = __builtin_amdgcn_mfma_f32_16x16x32_bf16(av, p0, acc1[g][0], 0, 0, 0);
        acc1[g][1] = __builtin_amdgcn_mfma_f32_16x16x32_bf16(av, p1, acc1[g][1], 0, 0, 0);
    }
    // merged-loop prologue: 3 pairs (W2,Pp interleaved) = 6 loads in flight
    short8 rbW[4], rbP[4];
    const bf16* Wb2 = W2p + (size_t)(ch * 16 + wid) * 8192 + laneE;
    const bf16* WbE = Pp  + (size_t)(ch * 16 + wid) * 8192 + laneE;
    GLD1(rbW[0], Wb2);        GLD1(rbP[0], WbE);
    GLD1(rbW[1], Wb2 + 512);  GLD1(rbP[1], WbE + 512);
    GLD1(rbW[2], Wb2 + 1024); GLD1(rbP[2], WbE + 1024);
    // L1 epilogue (hides prologue latency)
#pragma unroll
    for (int g = 0; g < 2; ++g)
#pragma unroll
        for (int f = 0; f < 2; ++f) {
            int col = wid * 32 + f * 16 + r;
#pragma unroll
            for (int v = 0; v < 4; ++v) {
                int row = g * 16 + kq * 4 + v;
                float h = tanh_fast(acc1[g][f][v] + bias1[f]);
                st_swz(h1, row, col, 512, h);
                st_swz(at, row, col, 512, fmaf(-h, h, 1.0f));
            }
        }
    LGKMBAR();    // h1/at visible; ring loads stay in flight

    // ---- merged L2 || E: one 16-step loop, 2 streams, 4 MFMA/step ----
    f32x4 acc2[2] = {};   // h1 @ W2
    f32x4 accE[2] = {};   // at @ P
#pragma unroll
    for (int s = 0; s < 16; ++s) {
        // hoisted A-fragment ds_reads (latency overlaps the vmcnt stall)
        int co = (((s * 4 + kq) ^ rx) << 3);
        short8 a1v[2], aav[2];
#pragma unroll
        for (int g = 0; g < 2; ++g) {
            a1v[g] = *(const short8*)(h1 + (g * 16 + r) * 512 + co);
            aav[g] = *(const short8*)(at + (g * 16 + r) * 512 + co);
        }
        if (s + 3 < 16) {
            GLD1(rbW[(s + 3) & 3], Wb2 + (s + 3) * 512);
            GLD1(rbP[(s + 3) & 3], WbE + (s + 3) * 512);
            WAITV(6);
        } else if (s + 2 < 16) { WAITV(4); }
        else if (s + 1 < 16)   { WAITV(2); }
        else                   { WAITV(0); }
#pragma unroll
        for (int g = 0; g < 2; ++g) {
            acc2[g] = __builtin_amdgcn_mfma_f32_16x16x32_bf16(a1v[g], rbW[s & 3], acc2[g], 0, 0, 0);
            accE[g] = __builtin_amdgcn_mfma_f32_16x16x32_bf16(aav[g], rbP[s & 3], accE[g], 0, 0, 0);
        }
    }
    // epilogue: h2 + bsq from acc2; L3 prefetch; trace from accE*bsq
    f32x4 bsq[2];
    {
        int colL = wid * 16 + r;
#pragma unroll
        for (int g = 0; g < 2; ++g)
#pragma unroll
            for (int v = 0; v < 4; ++v) {
                int row = g * 16 + kq * 4 + v;
                float h = tanh_fast(acc2[g][v] + bias2);
                st_swz(h2, row, colL, 256, h);
                bsq[g][v] = fmaf(-h, h, 1.0f);
            }
        const int kw = wid & 7;
        const bf16* Wb3 = W3p + (size_t)(ch * 8 + kw) * 2048 + laneE;
        GLD4(q0, q1, q2, q3, Wb3);
#pragma unroll
        for (int g = 0; g < 2; ++g)
#pragma unroll
            for (int v = 0; v < 4; ++v) {
                float p = accE[g][v] * bsq[g][v];
                p += __shfl_xor(p, 1);
                p += __shfl_xor(p, 2);
                p += __shfl_xor(p, 4);
                p += __shfl_xor(p, 8);
                if (r == 0) trp[wid * 32 + g * 16 + kq * 4 + v] = p;
            }
    }
    LGKMBAR();    // h2/trp visible; h1/at reads done -> vp overlay safe

    // ---- L3: v-partial = h2 @ W3 (this half's k); 8 kw x 2 row-halves ----
    {
        const int kw = wid & 7, rp = wid >> 3;
        f32x4 c0 = {}, c1 = {}, c2 = {}, c3 = {};
        short8 av = *(const short8*)(h2 + (rp * 16 + r) * 256 + (((kw * 4 + kq) ^ rx) << 3));
        WAITV(0);
        c0 = __builtin_amdgcn_mfma_f32_16x16x32_bf16(av, q0, c0, 0, 0, 0);
        c1 = __builtin_amdgcn_mfma_f32_16x16x32_bf16(av, q1, c1, 0, 0, 0);
        c2 = __builtin_amdgcn_mfma_f32_16x16x32_bf16(av, q2, c2, 0, 0, 0);
        c3 = __builtin_amdgcn_mfma_f32_16x16x32_bf16(av, q3, c3, 0, 0, 0);
#pragma unroll
        for (int v = 0; v < 4; ++v) {
            int row = rp * 16 + kq * 4 + v;
            vp[kw * 2048 + row * 64 + 0 * 16 + r] = c0[v];
            vp[kw * 2048 + row * 64 + 1 * 16 + r] = c1[v];
            vp[kw * 2048 + row * 64 + 2 * 16 + r] = c2[v];
            vp[kw * 2048 + row * 64 + 3 * 16 + r] = c3[v];
        }
    }
    LGKMBAR();

    // ---- final: reduce 8 k-chunk partials; atomicAdd v and trace ----
#pragma unroll
    for (int it = 0; it < 2; ++it) {
        int i = it * 1024 + tid;
        int row = i >> 6, col = i & 63;
        float s = 0.f;
#pragma unroll
        for (int kw = 0; kw < 8; ++kw) s += vp[kw * 2048 + i];
        atomicAdd(outV + (size_t)(bm + row) * DD + col, s);
    }
    if (tid < 32) {
        float s = 0.f;
#pragma unroll
        for (int w = 0; w < 16; ++w) s += trp[w * 32 + tid];
        atomicAdd(outTr + bm + tid, -s);
    }
}

extern "C" void kernel_launch(void* const* d_in, const int* in_sizes, int n_in,
                              void* d_out, int out_size, void* d_ws, size_t ws_size,
                              hipStream_t stream)
{
    const float* z  = (const float*)d_in[0];
    const float* t  = (const float*)d_in[2];
    const float* W1 = (const float*)d_in[3];
    const float* b1 = (const float*)d_in[4];
    const float* W2 = (const float*)d_in[5];
    const float* b2 = (const float*)d_in[6];
    const float* W3 = (const float*)d_in[7];
    const float* b3 = (const float*)d_in[8];
    float* out = (float*)d_out;                 // v [4096*64] then dlogp [4096]
    float* out_tr = out + (size_t)BB * DD;

    char* w = (char*)d_ws;
    auto alloc = [&](size_t bytes) {
        char* p = w;
        w += (bytes + 255) & ~(size_t)255;
        return p;
    };
    bf16* W1p   = (bf16*)alloc((size_t)64  * 512 * 2);
    bf16* W2p   = (bf16*)alloc((size_t)512 * 512 * 2);
    bf16* W3p   = (bf16*)alloc((size_t)64  * 512 * 2);
    bf16* Pp    = (bf16*)alloc((size_t)512 * 512 * 2);
    float* b1eff = (float*)alloc((size_t)HH * 4);

    // prep: packs + P (512-block parallel) + b1eff + output init
    prep_kernel<<<933, 256, 0, stream>>>(t, W1, b1, W2, W3, b3,
                                         W1p, W2p, W3p, Pp, b1eff, out);
    fused_rows<<<128 * 2, 1024, 0, stream>>>(z, W1p, W2p, W3p, Pp,
                                             b1eff, b2, out, out_tr);
}

// Round 17
// 22.471 us; speedup vs baseline: 2.3538x; 1.0506x over previous
//
#include <hip/hip_runtime.h>
#include <hip/hip_bf16.h>

#define BB 4096   // batch
#define DD 64     // event dim
#define HH 512    // hidden

typedef short short8 __attribute__((ext_vector_type(8)));   // 8 bf16
typedef float f32x4  __attribute__((ext_vector_type(4)));
typedef __hip_bfloat16 bf16;

// branchless fast tanh: 1 - 2/(1+e^{2x}); exact limits at +-inf
__device__ __forceinline__ float tanh_fast(float x) {
    float e = __expf(2.0f * x);
    return 1.0f - __fdividef(2.0f, 1.0f + e);
}

// swizzled LDS bf16 store (scalar, kept for z staging)
__device__ __forceinline__ void st_swz(bf16* base, int row, int col, int rs, float v) {
    base[row * rs + ((((col >> 3) ^ (row & 7))) << 3) + (col & 7)] = __float2bfloat16(v);
}

// swizzled LDS store of 4 CONSECUTIVE cols (col % 4 == 0) as one b64 write
__device__ __forceinline__ void st_swz64(bf16* base, int row, int col, int rs,
                                         float a, float b, float c, float d) {
    ushort4 v;
    v.x = __bfloat16_as_ushort(__float2bfloat16(a));
    v.y = __bfloat16_as_ushort(__float2bfloat16(b));
    v.z = __bfloat16_as_ushort(__float2bfloat16(c));
    v.w = __bfloat16_as_ushort(__float2bfloat16(d));
    int e = row * rs + ((((col >> 3) ^ (row & 7))) << 3) + (col & 7);
    *(ushort4*)(base + e) = v;
}

// single 1KB fragment load (proven R10/R12)
#define GLD1(dst, addr)                                                      \
  asm volatile("global_load_dwordx4 %0, %1, off" : "=&v"(dst) : "v"(addr))

// 2KB entry = 2 x 1KB
#define GLD2(e0, e1, addr)                                                   \
  asm volatile("global_load_dwordx4 %0, %2, off\n\t"                         \
               "global_load_dwordx4 %1, %2, off offset:1024"                 \
               : "=&v"(e0), "=&v"(e1) : "v"(addr))

// 4KB entry = 4 x 1KB
#define GLD4(e0, e1, e2, e3, addr)                                           \
  asm volatile("global_load_dwordx4 %0, %4, off\n\t"                         \
               "global_load_dwordx4 %1, %4, off offset:1024\n\t"             \
               "global_load_dwordx4 %2, %4, off offset:2048\n\t"             \
               "global_load_dwordx4 %3, %4, off offset:3072"                 \
               : "=&v"(e0), "=&v"(e1), "=&v"(e2), "=&v"(e3) : "v"(addr))

// counted wait + compiler motion fence (rule 18)
#define WAITV(n)                                                             \
  do { asm volatile("s_waitcnt vmcnt(" #n ")" ::: "memory");                 \
       __builtin_amdgcn_sched_barrier(0); } while (0)

// LDS-only barrier: raw s_barrier with lgkmcnt drain but NO vmcnt drain
#define LGKMBAR()                                                            \
  do { asm volatile("s_waitcnt lgkmcnt(0)" ::: "memory");                    \
       __builtin_amdgcn_s_barrier();                                         \
       __builtin_amdgcn_sched_barrier(0); } while (0)

// ===========================================================================
// Packed weights (16-col x 32-k tiles, tile = 512 elems = 1KB; lane l:
// kq=l>>4, r=l&15 owns B[col=base+r][k=kbase+kq*8+j], j=0..7 = 16B).
// MFMA A/B fragment layouts are identical, so these serve as A-operands in
// the SWAPPED scheme mfma(Wfrag, actfrag) -> D[wcol][batchrow] (lane holds
// 4 consecutive wcols of one batch row -> packed b64 epilogue stores).
//   W1p: T = w*4 + s*2 + f ; W2p/Pp: T = cw*16 + s ; W3p: T = q*4 + f
//
// Grid (933 blocks x 256):
//   [0,160)    pack W1p/W2p/W3p (4 tiles/block)
//   [160,672)  Pp: ONE tile per block, 4 waves split d-reduction 4-ways
//   672        b1eff
//   [673,933)  output init (v = b3 broadcast, trace = 0)
// ===========================================================================
__global__ __launch_bounds__(256) void prep_kernel(
    const float* __restrict__ t, const float* __restrict__ W1,
    const float* __restrict__ b1, const float* __restrict__ W2,
    const float* __restrict__ W3, const float* __restrict__ b3,
    bf16* __restrict__ W1p, bf16* __restrict__ W2p, bf16* __restrict__ W3p,
    bf16* __restrict__ Pp, float* __restrict__ b1eff, float* __restrict__ out)
{
    const int tid  = threadIdx.x;
    const int bx   = blockIdx.x;
    const int lane = tid & 63;
    const int r    = lane & 15;
    const int kq   = lane >> 4;

    if (bx < 160) {
        int T = bx * 4 + (tid >> 6);     // 0..639
        const float* src;
        bf16* dst;
        int stride;
        if (T < 64) {            // W1p
            int w = T >> 2, s = (T >> 1) & 1, f = T & 1;
            src = W1 + (size_t)(s * 32 + kq * 8) * HH + (w * 2 + f) * 16 + r;
            stride = HH;
            dst = W1p + (size_t)T * 512 + lane * 8;
        } else if (T < 576) {    // W2p
            int tt = T - 64;
            int cw = tt >> 4, s = tt & 15;
            src = W2 + (size_t)(s * 32 + kq * 8) * HH + cw * 16 + r;
            stride = HH;
            dst = W2p + (size_t)tt * 512 + lane * 8;
        } else {                 // W3p
            int tt = T - 576;
            int q = tt >> 2, f = tt & 3;
            src = W3 + (size_t)(q * 32 + kq * 8) * DD + f * 16 + r;
            stride = DD;
            dst = W3p + (size_t)tt * 512 + lane * 8;
        }
        short8 v;
#pragma unroll
        for (int j = 0; j < 8; ++j)
            v[j] = (short)__bfloat16_as_ushort(__float2bfloat16(src[(size_t)j * stride]));
        *(short8*)dst = v;
    } else if (bx < 672) {
        // Pp tile pt (one per block): out-col k = cw*16+r, reduce j = s*32+kq*8+jj
        __shared__ float part[4][64][8];
        int pt = bx - 160;                       // 0..511
        int cw = pt >> 4, s = pt & 15;
        int k  = cw * 16 + r;
        int j0 = s * 32 + kq * 8;
        int wq = tid >> 6;
        float acc[8] = {};
        const float* w3row = W3 + (size_t)k * DD + wq * 16;
        const float* w1base = W1 + (size_t)(wq * 16) * HH + j0;
#pragma unroll
        for (int d = 0; d < 16; ++d) {
            float w3 = w3row[d];
            const float4* w1p4 = (const float4*)(w1base + (size_t)d * HH);
            float4 x = w1p4[0], y = w1p4[1];
            acc[0] += x.x * w3; acc[1] += x.y * w3;
            acc[2] += x.z * w3; acc[3] += x.w * w3;
            acc[4] += y.x * w3; acc[5] += y.y * w3;
            acc[6] += y.z * w3; acc[7] += y.w * w3;
        }
        *(f32x4*)&part[wq][lane][0] = *(f32x4*)&acc[0];
        *(f32x4*)&part[wq][lane][4] = *(f32x4*)&acc[4];
        __syncthreads();
        if (wq == 0) {
            short8 v;
#pragma unroll
            for (int j = 0; j < 8; ++j) {
                float ssum = part[0][lane][j] + part[1][lane][j] +
                             part[2][lane][j] + part[3][lane][j];
                v[j] = (short)__bfloat16_as_ushort(
                    __float2bfloat16(ssum * W2[(size_t)(j0 + j) * HH + k]));
            }
            *(short8*)(Pp + (size_t)pt * 512 + lane * 8) = v;
        }
    } else if (bx == 672) {
        float tv = t[0];
        b1eff[tid]       = b1[tid]       + tv * W1[(size_t)64 * HH + tid];
        b1eff[tid + 256] = b1[tid + 256] + tv * W1[(size_t)64 * HH + tid + 256];
    } else {
        int idx = (bx - 673) * 1024 + tid * 4;   // 260 blocks, exact cover
        if (idx < BB * DD) {
            int col = idx & 63;
            *(float4*)(out + idx) =
                make_float4(b3[col], b3[col + 1], b3[col + 2], b3[col + 3]);
        } else {
            *(float4*)(out + idx) = make_float4(0.f, 0.f, 0.f, 0.f);
        }
    }
}

// ---------------------------------------------------------------------------
// fused_rows: R13/R16 structure with SWAPPED MFMA operands. 256 blocks x
// 1024 threads (16 waves); bid = rt*2 + ch. D[wcol][batchrow] layout ->
// each lane owns 4 consecutive out-cols of one row -> b64 packed epilogue
// stores (4x fewer LDS store ops, no shfl), 2-shfl trace reduce, float4 vp.
// Ring/wait/barrier schedule byte-identical to R16.
// ---------------------------------------------------------------------------
__global__ __launch_bounds__(1024, 2) void fused_rows(
    const float* __restrict__ z, const bf16* __restrict__ W1p,
    const bf16* __restrict__ W2p, const bf16* __restrict__ W3p,
    const bf16* __restrict__ Pp, const float* __restrict__ b1eff,
    const float* __restrict__ b2,
    float* __restrict__ outV, float* __restrict__ outTr)
{
    __shared__ alignas(16) char smem[88064];
    bf16* zt   = (bf16*)smem;                 // [32][64]  swizzled (4 KB)
    bf16* h1   = (bf16*)(smem + 4096);        // [32][512] swizzled (32 KB)
    bf16* at   = (bf16*)(smem + 36864);       // [32][512] swizzled (32 KB)
    bf16* h2   = (bf16*)(smem + 69632);       // [32][256] swizzled (16 KB)
    float* trp = (float*)(smem + 86016);      // [16][32]           (2 KB)
    float* vp  = (float*)smem;                // [8][32][68] pad, overlays zt+h1+at

    const int tid  = threadIdx.x;
    const int wid  = tid >> 6;                // 0..15
    const int lane = tid & 63;
    const int r    = lane & 15;
    const int kq   = lane >> 4;
    const int rx   = r & 7;
    const int laneE = lane * 8;
    const int rt   = blockIdx.x >> 1;
    const int ch   = blockIdx.x & 1;
    const int bm   = rt * 32;

    // ---- preload biases (float4 per 4 consecutive cols) BEFORE asm loads ----
    float4 b1v0 = *(const float4*)(b1eff + wid * 32 + kq * 4);
    float4 b1v1 = *(const float4*)(b1eff + wid * 32 + 16 + kq * 4);
    float4 b2v  = *(const float4*)(b2 + ch * 256 + wid * 16 + kq * 4);
    asm volatile("" :: "v"(b1v0.x), "v"(b1v0.y), "v"(b1v0.z), "v"(b1v0.w),
                       "v"(b1v1.x), "v"(b1v1.y), "v"(b1v1.z), "v"(b1v1.w),
                       "v"(b2v.x), "v"(b2v.y), "v"(b2v.z), "v"(b2v.w));
    float b1a[2][4] = {{b1v0.x, b1v0.y, b1v0.z, b1v0.w},
                       {b1v1.x, b1v1.y, b1v1.z, b1v1.w}};
    float b2a[4] = {b2v.x, b2v.y, b2v.z, b2v.w};

    // ---- stage z: 32x64 f32 -> bf16 swizzled (2 elems/thread) ----
    {
        int i = tid * 2;
        int row = i >> 6, col = i & 63;
        float2 v = *(const float2*)(z + (size_t)(bm + row) * DD + col);
        st_swz(zt, row, col,     64, v.x);
        st_swz(zt, row, col + 1, 64, v.y);
    }

    // ---- L1 prefetch: wave strip = 32 cols, 2 entries (K=64) ----
    short8 q0, q1, q2, q3, p0, p1;
    const bf16* Wb1 = W1p + (size_t)wid * 2048 + laneE;
    GLD2(q0, q1, Wb1);
    GLD2(p0, p1, Wb1 + 1024);
    LGKMBAR();    // zt visible; L1 weight loads stay in flight

    // ---- L1 (swapped): acc1[g][f] = W1frag[f] x zfrag[g] ----
    f32x4 acc1[2][2] = {};    // [g=rowgroup][f=colfrag]
    WAITV(2);
#pragma unroll
    for (int g = 0; g < 2; ++g) {
        short8 av = *(const short8*)(zt + (g * 16 + r) * 64 + ((kq ^ rx) << 3));
        acc1[g][0] = __builtin_amdgcn_mfma_f32_16x16x32_bf16(q0, av, acc1[g][0], 0, 0, 0);
        acc1[g][1] = __builtin_amdgcn_mfma_f32_16x16x32_bf16(q1, av, acc1[g][1], 0, 0, 0);
    }
    WAITV(0);
#pragma unroll
    for (int g = 0; g < 2; ++g) {
        short8 av = *(const short8*)(zt + (g * 16 + r) * 64 + (((4 + kq) ^ rx) << 3));
        acc1[g][0] = __builtin_amdgcn_mfma_f32_16x16x32_bf16(p0, av, acc1[g][0], 0, 0, 0);
        acc1[g][1] = __builtin_amdgcn_mfma_f32_16x16x32_bf16(p1, av, acc1[g][1], 0, 0, 0);
    }
    // merged-loop prologue: 3 pairs (W2,Pp interleaved) = 6 loads in flight
    short8 rbW[4], rbP[4];
    const bf16* Wb2 = W2p + (size_t)(ch * 16 + wid) * 8192 + laneE;
    const bf16* WbE = Pp  + (size_t)(ch * 16 + wid) * 8192 + laneE;
    GLD1(rbW[0], Wb2);        GLD1(rbP[0], WbE);
    GLD1(rbW[1], Wb2 + 512);  GLD1(rbP[1], WbE + 512);
    GLD1(rbW[2], Wb2 + 1024); GLD1(rbP[2], WbE + 1024);
    // L1 epilogue: lane owns (row=g*16+r, cols wid*32+f*16+kq*4 ..+3) -> b64
#pragma unroll
    for (int g = 0; g < 2; ++g)
#pragma unroll
        for (int f = 0; f < 2; ++f) {
            float hv[4], avv[4];
#pragma unroll
            for (int v = 0; v < 4; ++v) {
                hv[v]  = tanh_fast(acc1[g][f][v] + b1a[f][v]);
                avv[v] = fmaf(-hv[v], hv[v], 1.0f);
            }
            int rowq = g * 16 + r;
            int colq = wid * 32 + f * 16 + kq * 4;
            st_swz64(h1, rowq, colq, 512, hv[0], hv[1], hv[2], hv[3]);
            st_swz64(at, rowq, colq, 512, avv[0], avv[1], avv[2], avv[3]);
        }
    LGKMBAR();    // h1/at visible; ring loads stay in flight

    // ---- merged L2 || E (swapped): one 16-step loop, 4 MFMA/step ----
    f32x4 acc2[2] = {};   // W2frag x h1frag -> [wcol][row]
    f32x4 accE[2] = {};   // Pfrag  x atfrag
#pragma unroll
    for (int s = 0; s < 16; ++s) {
        int co = (((s * 4 + kq) ^ rx) << 3);
        short8 a1v[2], aav[2];
#pragma unroll
        for (int g = 0; g < 2; ++g) {
            a1v[g] = *(const short8*)(h1 + (g * 16 + r) * 512 + co);
            aav[g] = *(const short8*)(at + (g * 16 + r) * 512 + co);
        }
        if (s + 3 < 16) {
            GLD1(rbW[(s + 3) & 3], Wb2 + (s + 3) * 512);
            GLD1(rbP[(s + 3) & 3], WbE + (s + 3) * 512);
            WAITV(6);
        } else if (s + 2 < 16) { WAITV(4); }
        else if (s + 1 < 16)   { WAITV(2); }
        else                   { WAITV(0); }
#pragma unroll
        for (int g = 0; g < 2; ++g) {
            acc2[g] = __builtin_amdgcn_mfma_f32_16x16x32_bf16(rbW[s & 3], a1v[g], acc2[g], 0, 0, 0);
            accE[g] = __builtin_amdgcn_mfma_f32_16x16x32_bf16(rbP[s & 3], aav[g], accE[g], 0, 0, 0);
        }
    }
    // epilogue: h2 (b64 packed) + bsq; L3 prefetch; trace (2-shfl reduce)
    f32x4 bsq[2];
    {
#pragma unroll
        for (int g = 0; g < 2; ++g) {
            float hv[4];
#pragma unroll
            for (int v = 0; v < 4; ++v) {
                hv[v] = tanh_fast(acc2[g][v] + b2a[v]);
                bsq[g][v] = fmaf(-hv[v], hv[v], 1.0f);
            }
            st_swz64(h2, g * 16 + r, wid * 16 + kq * 4, 256,
                     hv[0], hv[1], hv[2], hv[3]);
        }
        const int kw = wid & 7;
        const bf16* Wb3 = W3p + (size_t)(ch * 8 + kw) * 2048 + laneE;
        GLD4(q0, q1, q2, q3, Wb3);
#pragma unroll
        for (int g = 0; g < 2; ++g) {
            float p = accE[g][0] * bsq[g][0] + accE[g][1] * bsq[g][1]
                    + accE[g][2] * bsq[g][2] + accE[g][3] * bsq[g][3];
            p += __shfl_xor(p, 16);
            p += __shfl_xor(p, 32);
            if (lane < 16) trp[wid * 32 + g * 16 + lane] = p;
        }
    }
    LGKMBAR();    // h2/trp visible; h1/at reads done -> vp overlay safe

    // ---- L3 (swapped): v-partial = W3frag x h2frag; float4 vp stores ----
    {
        const int kw = wid & 7, rp = wid >> 3;
        f32x4 c0 = {}, c1 = {}, c2 = {}, c3 = {};
        short8 av = *(const short8*)(h2 + (rp * 16 + r) * 256 + (((kw * 4 + kq) ^ rx) << 3));
        WAITV(0);
        c0 = __builtin_amdgcn_mfma_f32_16x16x32_bf16(q0, av, c0, 0, 0, 0);
        c1 = __builtin_amdgcn_mfma_f32_16x16x32_bf16(q1, av, c1, 0, 0, 0);
        c2 = __builtin_amdgcn_mfma_f32_16x16x32_bf16(q2, av, c2, 0, 0, 0);
        c3 = __builtin_amdgcn_mfma_f32_16x16x32_bf16(q3, av, c3, 0, 0, 0);
        int base = kw * 2176 + (rp * 16 + r) * 68 + kq * 4;
        *(f32x4*)(vp + base)      = c0;
        *(f32x4*)(vp + base + 16) = c1;
        *(f32x4*)(vp + base + 32) = c2;
        *(f32x4*)(vp + base + 48) = c3;
    }
    LGKMBAR();

    // ---- final: reduce 8 k-chunk partials; atomicAdd v and trace ----
#pragma unroll
    for (int it = 0; it < 2; ++it) {
        int i = it * 1024 + tid;
        int row = i >> 6, col = i & 63;
        float s = 0.f;
#pragma unroll
        for (int kw = 0; kw < 8; ++kw) s += vp[kw * 2176 + row * 68 + col];
        atomicAdd(outV + (size_t)(bm + row) * DD + col, s);
    }
    if (tid < 32) {
        float s = 0.f;
#pragma unroll
        for (int w = 0; w < 16; ++w) s += trp[w * 32 + tid];
        atomicAdd(outTr + bm + tid, -s);
    }
}

extern "C" void kernel_launch(void* const* d_in, const int* in_sizes, int n_in,
                              void* d_out, int out_size, void* d_ws, size_t ws_size,
                              hipStream_t stream)
{
    const float* z  = (const float*)d_in[0];
    const float* t  = (const float*)d_in[2];
    const float* W1 = (const float*)d_in[3];
    const float* b1 = (const float*)d_in[4];
    const float* W2 = (const float*)d_in[5];
    const float* b2 = (const float*)d_in[6];
    const float* W3 = (const float*)d_in[7];
    const float* b3 = (const float*)d_in[8];
    float* out = (float*)d_out;                 // v [4096*64] then dlogp [4096]
    float* out_tr = out + (size_t)BB * DD;

    char* w = (char*)d_ws;
    auto alloc = [&](size_t bytes) {
        char* p = w;
        w += (bytes + 255) & ~(size_t)255;
        return p;
    };
    bf16* W1p   = (bf16*)alloc((size_t)64  * 512 * 2);
    bf16* W2p   = (bf16*)alloc((size_t)512 * 512 * 2);
    bf16* W3p   = (bf16*)alloc((size_t)64  * 512 * 2);
    bf16* Pp    = (bf16*)alloc((size_t)512 * 512 * 2);
    float* b1eff = (float*)alloc((size_t)HH * 4);

    // prep: packs + P (512-block parallel) + b1eff + output init
    prep_kernel<<<933, 256, 0, stream>>>(t, W1, b1, W2, W3, b3,
                                         W1p, W2p, W3p, Pp, b1eff, out);
    fused_rows<<<128 * 2, 1024, 0, stream>>>(z, W1p, W2p, W3p, Pp,
                                             b1eff, b2, out, out_tr);
}